// Round 8
// baseline (302.003 us; speedup 1.0000x reference)
//
#include <hip/hip_runtime.h>

// GaussianMixture energy on MI355X — round 8: k_inv mini-sweep made
// wave-synchronous (zero barriers in the 128-pivot serial chain).
// S=65536, D=128, K=8.
//
// Pipeline:
//  1. k_gamma : gamma = softmax(x@W + b) -> gamma-transposed gt[S/64][8][64]
//  2. k_xprep : bf16 copies of x: xb[S][128] row-major, xt[S/64][128][64] chunk-transposed
//  3. k_m2    : M2_k = (sqrt(g) x)^T (sqrt(g) x) via mfma_f32_16x16x32_bf16; msp, nkp
//  4. k_redmu : Nk, mu
//  5. k_sigma : sigma_k = M2_k/Nk - mu mu^T   (fp32)
//  6. k_inv   : blocked symmetric sweep -> Sigma^{-1} (bf16 out), v=Sigma^{-1}mu,
//               c2=mu.v, coef.  Mini-sweep = single wave 0, wave-synchronous.
//  7. k_maha  : y = x Sigma^{-1} via MFMA; A-frags + epilogue-x in registers;
//               maha = sum x*(y-2v)+c2; online LSE over k
//  8. k_final : energy = -sum

#define S_LEN 65536
#define D 128
#define K 8
#define NCH 32                    // k_m2 S-chunks (2048 samples each)
#define KSTEP 64                  // samples per xt chunk / MFMA K-tile pair
#define NXTCH (S_LEN / KSTEP)     // 1024
#define MB_S 128                  // k_maha samples per block
#define NMB (S_LEN / MB_S)        // 512

// workspace layout (float offsets)
#define OFF_GT 0
#define SZ_GT (NXTCH * K * KSTEP)            // 524288
#define OFF_M2P (OFF_GT + SZ_GT)
#define SZ_M2P (K * NCH * D * D)             // 4194304
#define OFF_MSP (OFF_M2P + SZ_M2P)
#define SZ_MSP (K * NCH * D)                 // 32768
#define OFF_NKP (OFF_MSP + SZ_MSP)
#define SZ_NKP (K * NCH)                     // 256
#define OFF_NK (OFF_NKP + SZ_NKP)
#define OFF_MU (OFF_NK + 8)
#define OFF_SIGMA (OFF_MU + K * D)
#define OFF_WV (OFF_SIGMA + K * D * D)
#define OFF_COEF (OFF_WV + K * D)
#define OFF_C2 (OFF_COEF + 8)
#define OFF_EPART (OFF_C2 + 8)
#define OFF_XB (OFF_EPART + NMB)             // bf16: S*128 shorts = 4194304 floats
#define SZ_XB (S_LEN * D / 2)
#define OFF_XT (OFF_XB + SZ_XB)
#define SZ_XT (S_LEN * D / 2)
#define OFF_BH (OFF_XT + SZ_XT)              // bf16 Sigma^{-1}: 65536 floats
// total ~13.3M floats (~53 MB)

#define LOG_2PI 1.8378770664093453f

typedef __attribute__((ext_vector_type(8))) short short8;
typedef __attribute__((ext_vector_type(4))) float f32x4;

__device__ __forceinline__ float bflo(unsigned u) { return __uint_as_float(u << 16); }
__device__ __forceinline__ float bfhi(unsigned u) { return __uint_as_float(u & 0xffff0000u); }
__device__ __forceinline__ float bfu(unsigned short u) { return __uint_as_float((unsigned)u << 16); }
__device__ __forceinline__ unsigned packbf(float a, float b) {  // lo=a, hi=b, RNE
  unsigned ua = __float_as_uint(a); ua = ua + 0x7fffu + ((ua >> 16) & 1);
  unsigned ub = __float_as_uint(b); ub = ub + 0x7fffu + ((ub >> 16) & 1);
  return (ua >> 16) | (ub & 0xffff0000u);
}

// ---------------------------------------------------------------- pass 1
__global__ __launch_bounds__(256) void k_gamma(const float* __restrict__ x,
                                               const float* __restrict__ W,
                                               const float* __restrict__ b,
                                               float* __restrict__ gt) {
  __shared__ float Wt[K][D];
  __shared__ float bl[K];
  int tid = threadIdx.x;
  for (int it = 0; it < 4; ++it) {
    int idx = it * 256 + tid;
    Wt[idx & 7][idx >> 3] = W[idx];
  }
  if (tid < K) bl[tid] = b[tid];
  __syncthreads();

  int s = blockIdx.x * 256 + tid;
  float li[K];
#pragma unroll
  for (int k = 0; k < K; ++k) li[k] = bl[k];
  const float4* xr = (const float4*)(x + (size_t)s * D);
#pragma unroll 8
  for (int i = 0; i < 32; ++i) {
    float4 xv = xr[i];
#pragma unroll
    for (int k = 0; k < K; ++k) {
      float4 wv = *(const float4*)&Wt[k][i * 4];
      li[k] += xv.x * wv.x + xv.y * wv.y + xv.z * wv.z + xv.w * wv.w;
    }
  }
  float m = li[0];
#pragma unroll
  for (int k = 1; k < K; ++k) m = fmaxf(m, li[k]);
  float p[K];
  float sum = 0.f;
#pragma unroll
  for (int k = 0; k < K; ++k) { p[k] = expf(li[k] - m); sum += p[k]; }
  float inv = 1.0f / sum;
  int ch = s >> 6, sl = s & 63;
#pragma unroll
  for (int k = 0; k < K; ++k) gt[(size_t)ch * (K * 64) + k * 64 + sl] = p[k] * inv;
}

// ---------------------------------------------------------------- pass 2
// bf16 copies of x: xb row-major, xt chunk-transposed [S/64][128 d][64 s]
__global__ __launch_bounds__(256) void k_xprep(const float* __restrict__ x,
                                               unsigned short* __restrict__ xb,
                                               unsigned short* __restrict__ xt) {
  __shared__ unsigned short xr[64 * 136];   // [64 s][128 d + 8 pad]
  int tid = threadIdx.x;
  for (int c = 0; c < 4; ++c) {
    int sb = blockIdx.x * 256 + c * 64;
    if (c) __syncthreads();
    {  // stage: thread covers sample s=tid>>2, d-block (tid&3)*32
      int s = tid >> 2, db = (tid & 3) * 32;
      const float4* src = (const float4*)(x + (size_t)(sb + s) * D + db);
#pragma unroll
      for (int j = 0; j < 4; ++j) {
        float4 v0 = src[j * 2], v1 = src[j * 2 + 1];
        unsigned u0 = packbf(v0.x, v0.y), u1 = packbf(v0.z, v0.w);
        unsigned u2 = packbf(v1.x, v1.y), u3 = packbf(v1.z, v1.w);
        uint4 o = {u0, u1, u2, u3};
        *(uint4*)&xr[s * 136 + db + j * 8] = o;
      }
    }
    __syncthreads();
    {  // xb write: thread f -> 64B row-major
      int s = tid >> 2, u0 = (tid & 3) * 4;
      uint4* dst = (uint4*)(xb + (size_t)(sb + s) * D) + u0;
#pragma unroll
      for (int j = 0; j < 4; ++j) dst[j] = *(const uint4*)&xr[s * 136 + (u0 + j) * 8];
    }
    {  // xt write: thread f -> 64B of [d][64 s]
      int d = tid >> 1, lu0 = (tid & 1) * 4;
      uint4* dst = (uint4*)(xt + (size_t)(sb >> 6) * (D * 64) + d * 64) + lu0;
#pragma unroll
      for (int j = 0; j < 4; ++j) {
        int s0 = (lu0 + j) * 8;
        unsigned w[4];
#pragma unroll
        for (int q = 0; q < 4; ++q) {
          unsigned lo = xr[(s0 + 2 * q) * 136 + d];
          unsigned hi = xr[(s0 + 2 * q + 1) * 136 + d];
          w[q] = lo | (hi << 16);
        }
        uint4 o = {w[0], w[1], w[2], w[3]};
        dst[j] = o;
      }
    }
  }
}

// ---------------------------------------------------------------- pass 3
// M2_k partial over 2048-sample chunk via MFMA; z = sqrt(g)*x staged in LDS.
__global__ __launch_bounds__(256) void k_m2(const unsigned short* __restrict__ xt,
                                            const float* __restrict__ gt,
                                            float* __restrict__ m2p,
                                            float* __restrict__ msp,
                                            float* __restrict__ nkp) {
  __shared__ unsigned short zt[D * 64];     // 16KB, unit-swizzled
  __shared__ float gbuf[2][64], sgbuf[2][64];
  __shared__ float msred[256];
  int tid = threadIdx.x;
  int cblk = blockIdx.x, k = blockIdx.y;
  int ch0 = cblk * 32;

  int w = tid >> 6;
  int m0 = (w >> 1) * 64, n0 = (w & 1) * 64;
  int lg = (tid >> 4) & 3, ll = tid & 15;

  const uint4* xtg = (const uint4*)xt;
  uint4 xr[4];
  {
    const uint4* src = xtg + (size_t)ch0 * 1024 + tid * 4;
#pragma unroll
    for (int j = 0; j < 4; ++j) xr[j] = src[j];
  }
  float gacc = 0.f, gn = 0.f;
  if (tid < 64) {
    float g0 = gt[(size_t)ch0 * (K * 64) + k * 64 + tid];
    gbuf[0][tid] = g0; sgbuf[0][tid] = sqrtf(g0); gacc = g0;
    gn = gt[(size_t)(ch0 + 1) * (K * 64) + k * 64 + tid];
  }
  __syncthreads();

  f32x4 acc[4][4];
#pragma unroll
  for (int mi = 0; mi < 4; ++mi)
#pragma unroll
    for (int ni = 0; ni < 4; ++ni) acc[mi][ni] = (f32x4)0.f;

  float msa = 0.f;
  int dloc = tid >> 1;

  for (int t = 0; t < 32; ++t) {
    int cur = t & 1;
    // ---- z staging (uses xr regs + gbuf[cur])
#pragma unroll
    for (int j = 0; j < 4; ++j) {
      int lu = (tid & 1) * 4 + j, s0 = lu * 8;
      uint4 q = xr[j];
      float x0 = bflo(q.x), x1 = bfhi(q.x), x2 = bflo(q.y), x3 = bfhi(q.y);
      float x4 = bflo(q.z), x5 = bfhi(q.z), x6 = bflo(q.w), x7 = bfhi(q.w);
      float4 g0 = *(const float4*)&gbuf[cur][s0];
      float4 g1 = *(const float4*)&gbuf[cur][s0 + 4];
      float4 s0v = *(const float4*)&sgbuf[cur][s0];
      float4 s1v = *(const float4*)&sgbuf[cur][s0 + 4];
      msa += x0 * g0.x + x1 * g0.y + x2 * g0.z + x3 * g0.w +
             x4 * g1.x + x5 * g1.y + x6 * g1.z + x7 * g1.w;
      unsigned u0 = packbf(x0 * s0v.x, x1 * s0v.y);
      unsigned u1 = packbf(x2 * s0v.z, x3 * s0v.w);
      unsigned u2 = packbf(x4 * s1v.x, x5 * s1v.y);
      unsigned u3 = packbf(x6 * s1v.z, x7 * s1v.w);
      uint4 o = {u0, u1, u2, u3};
      *(uint4*)&zt[dloc * 64 + (lu ^ (dloc & 7)) * 8] = o;
    }
    // ---- gamma pipeline + prefetch next chunk
    if (tid < 64 && t + 1 < 32) {
      gbuf[cur ^ 1][tid] = gn; sgbuf[cur ^ 1][tid] = sqrtf(gn); gacc += gn;
    }
    if (t + 1 < 32) {
      const uint4* src = xtg + (size_t)(ch0 + t + 1) * 1024 + tid * 4;
#pragma unroll
      for (int j = 0; j < 4; ++j) xr[j] = src[j];
      if (tid < 64 && t + 2 < 32)
        gn = gt[(size_t)(ch0 + t + 2) * (K * 64) + k * 64 + tid];
    }
    __syncthreads();   // zt staged
    // ---- MFMA
#pragma unroll
    for (int ksub = 0; ksub < 2; ++ksub) {
      short8 af[4], bf_[4];
#pragma unroll
      for (int mi = 0; mi < 4; ++mi) {
        int dd = m0 + mi * 16 + ll;
        int ua = ksub * 4 + lg;
        af[mi] = *(const short8*)&zt[dd * 64 + (ua ^ (dd & 7)) * 8];
      }
#pragma unroll
      for (int ni = 0; ni < 4; ++ni) {
        int ee = n0 + ni * 16 + ll;
        int ub = ksub * 4 + lg;
        bf_[ni] = *(const short8*)&zt[ee * 64 + (ub ^ (ee & 7)) * 8];
      }
#pragma unroll
      for (int mi = 0; mi < 4; ++mi)
#pragma unroll
        for (int ni = 0; ni < 4; ++ni)
          acc[mi][ni] = __builtin_amdgcn_mfma_f32_16x16x32_bf16(
              af[mi], bf_[ni], acc[mi][ni], 0, 0, 0);
    }
    __syncthreads();   // MFMA done -> zt free
  }

  // ---- outputs
  size_t base = (size_t)(k * NCH + cblk) << 14;
#pragma unroll
  for (int mi = 0; mi < 4; ++mi)
#pragma unroll
    for (int ni = 0; ni < 4; ++ni)
#pragma unroll
      for (int r = 0; r < 4; ++r) {
        int row = m0 + mi * 16 + lg * 4 + r;
        int col = n0 + ni * 16 + ll;
        m2p[base + row * D + col] = acc[mi][ni][r];
      }
  msred[tid] = msa;
  __syncthreads();
  if (tid < 128) msp[(size_t)(k * NCH + cblk) * D + tid] = msred[2 * tid] + msred[2 * tid + 1];
  if (tid < 64) {
    float v = gacc;
#pragma unroll
    for (int off = 1; off < 64; off <<= 1) v += __shfl_xor(v, off);
    if (tid == 0) nkp[k * NCH + cblk] = v;
  }
}

// ---------------------------------------------------------------- pass 4a
__global__ __launch_bounds__(256) void k_redmu(const float* __restrict__ msp,
                                               const float* __restrict__ nkp,
                                               float* __restrict__ Nk,
                                               float* __restrict__ mu) {
  __shared__ float sNk[K];
  int tid = threadIdx.x;
  if (tid < K) {
    float s = 0.f;
    for (int c = 0; c < NCH; ++c) s += nkp[tid * NCH + c];
    sNk[tid] = s;
    Nk[tid] = s;
  }
  __syncthreads();
  for (int it = 0; it < (K * D) / 256; ++it) {
    int idx = it * 256 + tid;
    int k = idx >> 7;
    float s = 0.f;
    for (int c = 0; c < NCH; ++c) s += msp[(size_t)(k * NCH + c) * D + (idx & 127)];
    mu[idx] = s / sNk[k];
  }
}

// ---------------------------------------------------------------- pass 4b
__global__ __launch_bounds__(256) void k_sigma(const float* __restrict__ m2p,
                                               const float* __restrict__ Nk,
                                               const float* __restrict__ mu,
                                               float* __restrict__ sigma) {
  int tid = threadIdx.x;
  int k = blockIdx.y;
  int flat = blockIdx.x * 256 + tid;
  int d = flat >> 7, e = flat & 127;
  float s = 0.f;
  for (int c = 0; c < NCH; ++c) s += m2p[((size_t)(k * NCH + c) << 14) + flat];
  sigma[((size_t)k << 14) + flat] = s / Nk[k] - mu[k * D + d] * mu[k * D + e];
}

// ---------------------------------------------------------------- pass 5
// Blocked symmetric sweep -> Sigma^{-1} (bf16 out), v = Sigma^{-1} mu, c2 = mu.v
// Mini-sweep of the 32x32 pivot block runs on wave 0 ONLY, wave-synchronous
// (LDS instrs within a wave are ordered; no block barriers in the pivot chain).
#define PBW 36
#define YTW 132
#define AROT(r, c) (((r) << 7) + ((((c) + (((r) >> 3) << 2))) & 127))
#define SWQ(o, p) { f32x4 rf_; rf_[0] = piv * (p).x; rf_[1] = piv * (p).y;      \
  rf_[2] = piv * (p).z; rf_[3] = piv * (p).w;                                   \
  (o).x = prw ? rf_[0] : (o).x - cv * rf_[0];                                   \
  (o).y = prw ? rf_[1] : (o).y - cv * rf_[1];                                   \
  (o).z = prw ? rf_[2] : (o).z - cv * rf_[2];                                   \
  (o).w = prw ? rf_[3] : (o).w - cv * rf_[3]; }
#define SETL(q) { if (cl == 0) (q).x = nv; else if (cl == 1) (q).y = nv;        \
  else if (cl == 2) (q).z = nv; else (q).w = nv; }

__global__ __launch_bounds__(256) void k_inv(const float* __restrict__ sigma,
                                             const float* __restrict__ Nk,
                                             const float* __restrict__ mu,
                                             unsigned short* __restrict__ Bh,
                                             float* __restrict__ vv,
                                             float* __restrict__ coef,
                                             float* __restrict__ c2) {
  __shared__ float A[D * D];
  __shared__ float Pb[32 * PBW];
  __shared__ float Cb[32 * 128];
  __shared__ float Yt[32 * YTW];
  __shared__ float Rb[32 * 128];
  __shared__ float mus[D];
  int tid = threadIdx.x;
  int k = blockIdx.x;
  const float* sg = sigma + ((size_t)k << 14);

#pragma unroll
  for (int i = 0; i < 16; ++i) {
    int f = tid + 256 * i;
    int r = f >> 5, c4 = (f & 31) << 2;
    *(float4*)&A[AROT(r, c4)] = *(const float4*)&sg[((size_t)f) << 2];
  }
  if (tid < D) mus[tid] = mu[k * D + tid];
  __syncthreads();

  float ldet = 0.f;
  int mr = tid >> 3, mq = tid & 7;
  int ci = tid >> 1, ch = tid & 1;
  int w = tid >> 6, l = tid & 63;
  int d0 = (((w >> 1) << 3) + (l >> 3)) * 8;
  int e0 = (((w & 1) << 3) + (l & 7)) * 8;

  for (int t = 0; t < 4; ++t) {
    int tb = t * 32;
    *(float4*)&Pb[mr * PBW + 4 * mq] = *(const float4*)&A[AROT(tb + mr, tb + 4 * mq)];
#pragma unroll
    for (int q = 0; q < 4; ++q) {
      int f = tid + 256 * q;
      int rr = f >> 5, cc4 = (f & 31) << 2;
      *(float4*)&Rb[rr * 128 + cc4] = *(const float4*)&A[AROT(tb + rr, cc4)];
    }
#pragma unroll
    for (int n4 = 0; n4 < 4; ++n4) {
      float4 q4 = *(const float4*)&A[AROT(ci, tb + 16 * ch + 4 * n4)];
      int nb = 16 * ch + 4 * n4;
      Cb[(nb + 0) * 128 + ci] = q4.x;
      Cb[(nb + 1) * 128 + ci] = q4.y;
      Cb[(nb + 2) * 128 + ci] = q4.z;
      Cb[(nb + 3) * 128 + ci] = q4.w;
    }
    __syncthreads();

    // ---- mini-sweep Pb on wave 0 only (32 rank-1 sweeps, no block barriers)
    if (w == 0) {
      int rr = l >> 1, h = l & 1;          // lane owns row rr, col half h
      float* own = &Pb[rr * PBW + h * 16];
      const int hb = h * 16;
      for (int c = 0; c < 32; ++c) {
        float dpv = Pb[c * PBW + c];
        float piv = 1.0f / dpv;
        ldet += logf(dpv);
        const float* prow = &Pb[c * PBW + hb];
        float4 p0 = *(const float4*)&prow[0];
        float4 p1 = *(const float4*)&prow[4];
        float4 p2 = *(const float4*)&prow[8];
        float4 p3 = *(const float4*)&prow[12];
        float cv = Pb[rr * PBW + c];
        float4 o0 = *(const float4*)&own[0];
        float4 o1 = *(const float4*)&own[4];
        float4 o2 = *(const float4*)&own[8];
        float4 o3 = *(const float4*)&own[12];
        __builtin_amdgcn_wave_barrier();   // pin: all reads before writes
        bool prw = (rr == c);
        SWQ(o0, p0) SWQ(o1, p1) SWQ(o2, p2) SWQ(o3, p3)
        if ((c >> 4) == h) {               // lane's half contains pivot col
          float nv = prw ? -piv : cv * piv;
          int cq = (c >> 2) & 3, cl = c & 3;   // uniform
          if (cq == 0) SETL(o0)
          else if (cq == 1) SETL(o1)
          else if (cq == 2) SETL(o2)
          else SETL(o3)
        }
        *(float4*)&own[0] = o0;
        *(float4*)&own[4] = o1;
        *(float4*)&own[8] = o2;
        *(float4*)&own[12] = o3;
        __builtin_amdgcn_wave_barrier();   // pin: writes before next-iter reads
      }
    }
    __syncthreads();   // Pinv visible to all waves

    {
      int rs = tid >> 3, cs = tid & 7;
      float accY[4][4] = {};
#pragma unroll 8
      for (int n = 0; n < 32; ++n) {
        float4 cq4 = *(const float4*)&Cb[n * 128 + 4 * rs];
        float4 pq = *(const float4*)&Pb[n * PBW + 4 * cs];
        float ca[4] = {cq4.x, cq4.y, cq4.z, cq4.w};
        float pa[4] = {pq.x, pq.y, pq.z, pq.w};
#pragma unroll
        for (int q = 0; q < 4; ++q)
#pragma unroll
          for (int j = 0; j < 4; ++j) accY[q][j] -= ca[q] * pa[j];
      }
#pragma unroll
      for (int j = 0; j < 4; ++j) {
        float4 o = {accY[0][j], accY[1][j], accY[2][j], accY[3][j]};
        *(float4*)&Yt[(4 * cs + j) * YTW + 4 * rs] = o;
      }
    }
    __syncthreads();

    {
      float acc[8][8];
#pragma unroll
      for (int di = 0; di < 8; ++di)
#pragma unroll
        for (int e4 = 0; e4 < 2; ++e4) {
          float4 a = *(const float4*)&A[AROT(d0 + di, e0 + 4 * e4)];
          acc[di][e4 * 4 + 0] = a.x; acc[di][e4 * 4 + 1] = a.y;
          acc[di][e4 * 4 + 2] = a.z; acc[di][e4 * 4 + 3] = a.w;
        }
#pragma unroll 4
      for (int m = 0; m < 32; ++m) {
        float4 ya = *(const float4*)&Yt[m * YTW + d0];
        float4 yb = *(const float4*)&Yt[m * YTW + d0 + 4];
        float4 ra = *(const float4*)&Rb[m * 128 + e0];
        float4 rb2 = *(const float4*)&Rb[m * 128 + e0 + 4];
        float av[8] = {ya.x, ya.y, ya.z, ya.w, yb.x, yb.y, yb.z, yb.w};
        float bv[8] = {ra.x, ra.y, ra.z, ra.w, rb2.x, rb2.y, rb2.z, rb2.w};
#pragma unroll
        for (int di = 0; di < 8; ++di)
#pragma unroll
          for (int ei = 0; ei < 8; ++ei) acc[di][ei] -= av[di] * bv[ei];
      }
#pragma unroll
      for (int di = 0; di < 8; ++di)
#pragma unroll
        for (int e4 = 0; e4 < 2; ++e4) {
          float4 o = {acc[di][e4 * 4 + 0], acc[di][e4 * 4 + 1],
                      acc[di][e4 * 4 + 2], acc[di][e4 * 4 + 3]};
          *(float4*)&A[AROT(d0 + di, e0 + 4 * e4)] = o;
        }
    }
    __syncthreads();

#pragma unroll
    for (int qq = 0; qq < 4; ++qq) {
      int j0 = 4 * mq + 32 * qq;
      *(float4*)&A[AROT(tb + mr, j0)] = *(const float4*)&Yt[mr * YTW + j0];
    }
    if (ci < tb || ci >= tb + 32) {
#pragma unroll
      for (int n = 0; n < 16; ++n) {
        int mloc = 16 * ch + ((n + ci) & 15);
        A[AROT(ci, tb + mloc)] = Yt[mloc * YTW + ci];
      }
    }
    __syncthreads();
    *(float4*)&A[AROT(tb + mr, tb + 4 * mq)] = *(const float4*)&Pb[mr * PBW + 4 * mq];
    __syncthreads();
  }

  // ---- outputs: Bh = bf16(-A), v = -A mu, c2 = mu.v, coef
#pragma unroll
  for (int i = 0; i < 16; ++i) {
    int f = tid + 256 * i;
    int r = f >> 5, c4 = (f & 31) << 2;
    float4 a = *(const float4*)&A[AROT(r, c4)];
    unsigned u0 = packbf(-a.x, -a.y), u1 = packbf(-a.z, -a.w);
    uint2 o = {u0, u1};
    *(uint2*)(Bh + (size_t)k * (D * D) + f * 4) = o;
  }
  float c2part = 0.f;
  if (tid < D) {
    float s = 0.f;
#pragma unroll 8
    for (int q = 0; q < 32; ++q) {
      float4 a = *(const float4*)&A[AROT(tid, q << 2)];
      float4 m = *(const float4*)&mus[q << 2];
      s += a.x * m.x + a.y * m.y + a.z * m.z + a.w * m.w;
    }
    vv[k * D + tid] = -s;
    c2part = mus[tid] * (-s);
  }
  __syncthreads();
  {
    float v = c2part;
#pragma unroll
    for (int off = 1; off < 64; off <<= 1) v += __shfl_xor(v, off);
    if ((tid & 63) == 0) Pb[tid >> 6] = v;   // reuse Pb as scratch
  }
  __syncthreads();
  if (tid == 0) {
    c2[k] = Pb[0] + Pb[1];
    coef[k] = logf(Nk[k] * (1.0f / (float)S_LEN)) -
              0.5f * ((float)D * LOG_2PI + ldet);
  }
}

// ---------------------------------------------------------------- pass 6
// y = x Sigma^{-1} via MFMA. A-frags + epilogue-x in registers (k-invariant);
// full B_k (32KB) staged per phase, swizzled du^=(e&7); branchless online LSE.
__global__ __launch_bounds__(256) void k_maha(const unsigned short* __restrict__ xb,
                                              const unsigned short* __restrict__ Bh,
                                              const float* __restrict__ vv,
                                              const float* __restrict__ coef,
                                              const float* __restrict__ c2,
                                              float* __restrict__ epart) {
  __shared__ unsigned short Bt[D * D];      // 32KB, row-major in e, unit-swizzled
  __shared__ float vls[K * D];              // 4KB
  __shared__ float cfl[K], c2l[K];
  __shared__ float wsum[4];
  int tid = threadIdx.x;
  int bs = blockIdx.x * MB_S;
  int w = tid >> 6, l = tid & 63;
  int m0 = w * 32;
  int lg = (tid >> 4) & 3, ll = tid & 15;

  // ---- persistent A-fragments: af[mi][jj] = x[bs+m0+mi*16+ll][jj*32+lg*8 ..+8)
  short8 af[2][4];
#pragma unroll
  for (int mi = 0; mi < 2; ++mi) {
    const unsigned short* rp = xb + (size_t)(bs + m0 + mi * 16 + ll) * D;
#pragma unroll
    for (int jj = 0; jj < 4; ++jj)
      af[mi][jj] = *(const short8*)(rp + jj * 32 + lg * 8);
  }
  // ---- persistent epilogue x: ex[mi][r][ni] = x[bs+m0+mi*16+lg*4+r][ll+16*ni]
  unsigned short ex[2][4][8];
#pragma unroll
  for (int mi = 0; mi < 2; ++mi)
#pragma unroll
    for (int r = 0; r < 4; ++r) {
      const unsigned short* rp = xb + (size_t)(bs + m0 + mi * 16 + lg * 4 + r) * D + ll;
#pragma unroll
      for (int ni = 0; ni < 8; ++ni) ex[mi][r][ni] = rp[ni * 16];
    }

  // ---- stage constants
#pragma unroll
  for (int i = 0; i < 4; ++i) { int idx = i * 256 + tid; vls[idx] = vv[idx]; }
  if (tid < K) { cfl[tid] = coef[tid]; c2l[tid] = c2[tid]; }

  // ---- B prefetch k=0 (8 x 16B per thread = full 32KB per block)
  const uint4* bg = (const uint4*)Bh;       // B_k = 2048 16B-units, linear
  uint4 br[8];
#pragma unroll
  for (int j = 0; j < 8; ++j) br[j] = bg[j * 256 + tid];

  float mrun[2][4], srun[2][4];
#pragma unroll
  for (int mi = 0; mi < 2; ++mi)
#pragma unroll
    for (int r = 0; r < 4; ++r) { mrun[mi][r] = -1e30f; srun[mi][r] = 0.f; }

  for (int k = 0; k < K; ++k) {
    // ---- write staged B (swizzled): unit u -> row e=u>>4, du=u&15
#pragma unroll
    for (int j = 0; j < 8; ++j) {
      int u = j * 256 + tid;
      int e = u >> 4, du = u & 15;
      *(uint4*)&Bt[e * D + ((du ^ (e & 7)) << 3)] = br[j];
    }
    // ---- prefetch next k while MFMA phase runs
    if (k + 1 < K) {
      const uint4* src = bg + (size_t)(k + 1) * 2048;
#pragma unroll
      for (int j = 0; j < 8; ++j) br[j] = src[j * 256 + tid];
    }
    __syncthreads();   // Bt ready (first iter: vls/cfl too)

    // ---- MFMA: acc[mi][ni] over full D=128 contraction
    f32x4 acc[2][8];
#pragma unroll
    for (int mi = 0; mi < 2; ++mi)
#pragma unroll
      for (int ni = 0; ni < 8; ++ni) acc[mi][ni] = (f32x4)0.f;
#pragma unroll
    for (int jj = 0; jj < 4; ++jj) {
#pragma unroll
      for (int ni = 0; ni < 8; ++ni) {
        int e = ni * 16 + ll;
        int du = jj * 4 + lg;
        short8 bfr = *(const short8*)&Bt[e * D + ((du ^ (e & 7)) << 3)];
#pragma unroll
        for (int mi = 0; mi < 2; ++mi)
          acc[mi][ni] = __builtin_amdgcn_mfma_f32_16x16x32_bf16(
              af[mi][jj], bfr, acc[mi][ni], 0, 0, 0);
      }
    }

    // ---- epilogue: part = sum_col x*(y - 2v); LSE update (branchless)
    float part[2][4] = {};
#pragma unroll
    for (int ni = 0; ni < 8; ++ni) {
      int col = ni * 16 + ll;
      float w2 = -2.0f * vls[k * D + col];
#pragma unroll
      for (int mi = 0; mi < 2; ++mi)
#pragma unroll
        for (int r = 0; r < 4; ++r)
          part[mi][r] += bfu(ex[mi][r][ni]) * (acc[mi][ni][r] + w2);
    }
#pragma unroll
    for (int mi = 0; mi < 2; ++mi)
#pragma unroll
      for (int r = 0; r < 4; ++r) {
        float p = part[mi][r];
        p += __shfl_xor(p, 1); p += __shfl_xor(p, 2);
        p += __shfl_xor(p, 4); p += __shfl_xor(p, 8);
        float a = cfl[k] - 0.5f * (p + c2l[k]);
        float mn = fmaxf(mrun[mi][r], a);
        srun[mi][r] = srun[mi][r] * expf(mrun[mi][r] - mn) + expf(a - mn);
        mrun[mi][r] = mn;
      }
    __syncthreads();   // MFMA/epilogue done -> Bt free for next k
  }

  // ---- block reduction of log-densities
  float v = 0.f;
#pragma unroll
  for (int mi = 0; mi < 2; ++mi)
#pragma unroll
    for (int r = 0; r < 4; ++r) v += mrun[mi][r] + logf(srun[mi][r]);
  v += __shfl_xor(v, 16);
  v += __shfl_xor(v, 32);
  if (l == 0) wsum[w] = v;
  __syncthreads();
  if (tid == 0) epart[blockIdx.x] = wsum[0] + wsum[1] + wsum[2] + wsum[3];
}

// ---------------------------------------------------------------- pass 7
__global__ __launch_bounds__(256) void k_final(const float* __restrict__ epart,
                                               float* __restrict__ out) {
  __shared__ double sw[4];
  int tid = threadIdx.x;
  double a = (double)epart[tid] + (double)epart[tid + 256];
#pragma unroll
  for (int off = 1; off < 64; off <<= 1) a += __shfl_xor(a, off);
  if ((tid & 63) == 0) sw[tid >> 6] = a;
  __syncthreads();
  if (tid == 0) out[0] = (float)(-(sw[0] + sw[1] + sw[2] + sw[3]));
}

// ----------------------------------------------------------------
extern "C" void kernel_launch(void* const* d_in, const int* in_sizes, int n_in,
                              void* d_out, int out_size, void* d_ws, size_t ws_size,
                              hipStream_t stream) {
  (void)in_sizes; (void)n_in; (void)out_size; (void)ws_size;
  const float* x = (const float*)d_in[0];
  const float* W = (const float*)d_in[1];
  const float* b = (const float*)d_in[2];
  float* out = (float*)d_out;
  float* ws = (float*)d_ws;

  float* gtp   = ws + OFF_GT;
  float* m2p   = ws + OFF_M2P;
  float* msp   = ws + OFF_MSP;
  float* nkp   = ws + OFF_NKP;
  float* Nk    = ws + OFF_NK;
  float* mu    = ws + OFF_MU;
  float* sigma = ws + OFF_SIGMA;
  float* wvp   = ws + OFF_WV;
  float* coefp = ws + OFF_COEF;
  float* c2p   = ws + OFF_C2;
  float* epart = ws + OFF_EPART;
  unsigned short* xb = (unsigned short*)(ws + OFF_XB);
  unsigned short* xt = (unsigned short*)(ws + OFF_XT);
  unsigned short* Bh = (unsigned short*)(ws + OFF_BH);

  k_gamma<<<S_LEN / 256, 256, 0, stream>>>(x, W, b, gtp);
  k_xprep<<<S_LEN / 256, 256, 0, stream>>>(x, xb, xt);
  k_m2<<<dim3(NCH, K), 256, 0, stream>>>(xt, gtp, m2p, msp, nkp);
  k_redmu<<<1, 256, 0, stream>>>(msp, nkp, Nk, mu);
  k_sigma<<<dim3(64, K), 256, 0, stream>>>(m2p, Nk, mu, sigma);
  k_inv<<<K, 256, 0, stream>>>(sigma, Nk, mu, Bh, wvp, coefp, c2p);
  k_maha<<<NMB, 256, 0, stream>>>(xb, Bh, wvp, coefp, c2p, epart);
  k_final<<<1, 256, 0, stream>>>(epart, out);
}